// Round 1
// baseline (380.870 us; speedup 1.0000x reference)
//
#include <hip/hip_runtime.h>
#include <hip/hip_bf16.h>

// Rulebook sparse conv: out[out_idx[k,r]] += x[in_idx[k,r]] @ W[k] ; out += bias
// K=27 offsets, R=50000 rules each, Cin=Cout=64.
// Strategy: per block = 256 rules of one offset. Gather x rows f32->bf16 into
// swizzled LDS, W_k^T f32->bf16 into swizzled LDS, 4 waves x mfma 16x16x32,
// atomic scatter-add f32.

typedef __bf16 bf16x8_t __attribute__((ext_vector_type(8)));
typedef float f32x4_t __attribute__((ext_vector_type(4)));

#define KOFF 27
#define RULES 50000
#define CIN 64
#define COUT 64
#define NOUT 150000
#define BR 256
#define BPK ((RULES + BR - 1) / BR) /* 196 */

__global__ __launch_bounds__(256) void init_out_kernel(
    const float* __restrict__ bias, float* __restrict__ out, int total4) {
  int i = blockIdx.x * blockDim.x + threadIdx.x;
  const int stride = gridDim.x * blockDim.x;
  for (; i < total4; i += stride) {
    const int c0 = (i * 4) & 63;
    float4 v;
    v.x = bias[c0 + 0];
    v.y = bias[c0 + 1];
    v.z = bias[c0 + 2];
    v.w = bias[c0 + 3];
    reinterpret_cast<float4*>(out)[i] = v;
  }
}

__global__ __launch_bounds__(256) void spconv_kernel(
    const float* __restrict__ x,      // [N_IN, 64]
    const float* __restrict__ w,      // [K, 64, 64] (c,o)
    const int* __restrict__ in_idx,   // [K*R]
    const int* __restrict__ out_idx,  // [K*R]
    float* __restrict__ out)          // [NOUT, 64]
{
  // LDS: A tile 256 rows x 64 ch bf16 (swizzled), B tile = W_k^T 64x64 bf16 (swizzled)
  __shared__ char lds[256 * 128 + 64 * 128];
  char* const Abase = lds;
  char* const Bbase = lds + 256 * 128;

  const int bid = blockIdx.x;
  const int k = bid / BPK;
  const int rblk = bid - k * BPK;
  const int rule0 = rblk * BR;  // rule offset within this k
  const int t = threadIdx.x;

  // ---- stage A: gather 256 x-rows, f32 -> bf16, swizzled LDS write ----
  {
    const int chunk = t & 7;  // which 16B bf16 chunk (8 channels)
    const int r0 = t >> 3;    // 32 rows per pass
#pragma unroll
    for (int pass = 0; pass < 8; ++pass) {
      const int r = r0 + pass * 32;
      const int rule = rule0 + r;
      bf16x8_t v;
      if (rule < RULES) {
        const int src = in_idx[(size_t)k * RULES + rule];
        const float* p = x + (size_t)src * CIN + chunk * 8;
        const float4 f0 = *reinterpret_cast<const float4*>(p);
        const float4 f1 = *reinterpret_cast<const float4*>(p + 4);
        v[0] = (__bf16)f0.x; v[1] = (__bf16)f0.y;
        v[2] = (__bf16)f0.z; v[3] = (__bf16)f0.w;
        v[4] = (__bf16)f1.x; v[5] = (__bf16)f1.y;
        v[6] = (__bf16)f1.z; v[7] = (__bf16)f1.w;
      } else {
#pragma unroll
        for (int e = 0; e < 8; ++e) v[e] = (__bf16)0.0f;
      }
      const int colByte = (chunk * 16) ^ ((r & 7) << 4);
      *reinterpret_cast<bf16x8_t*>(Abase + r * 128 + colByte) = v;
    }
  }

  // ---- stage B: W_k transpose -> LDS[o][c] bf16, swizzled ----
  {
    const int c = t >> 2;           // 0..63
    const int o0 = (t & 3) * 16;    // 0,16,32,48
    const float* wp = w + ((size_t)k * CIN + c) * COUT + o0;
#pragma unroll
    for (int j4 = 0; j4 < 4; ++j4) {
      const float4 f = *reinterpret_cast<const float4*>(wp + j4 * 4);
#pragma unroll
      for (int e = 0; e < 4; ++e) {
        const int o = o0 + j4 * 4 + e;
        const float val = (e == 0) ? f.x : (e == 1) ? f.y : (e == 2) ? f.z : f.w;
        const int addr = o * 128 + ((c * 2) ^ ((o & 7) << 4));
        *reinterpret_cast<__bf16*>(Bbase + addr) = (__bf16)val;
      }
    }
  }

  __syncthreads();

  // ---- MFMA: each wave computes 64 rules x 64 cols ----
  const int wid = t >> 6;
  const int l = t & 63;
  const int rA = l & 15;   // A row within 16 / D col
  const int g = l >> 4;    // k-group

  bf16x8_t af[4][2];
  bf16x8_t bfr[4][2];
#pragma unroll
  for (int m = 0; m < 4; ++m) {
#pragma unroll
    for (int kk = 0; kk < 2; ++kk) {
      const int r = wid * 64 + m * 16 + rA;
      const int colByte = (kk * 64 + g * 16) ^ ((r & 7) << 4);
      af[m][kk] = *reinterpret_cast<const bf16x8_t*>(Abase + r * 128 + colByte);
    }
  }
#pragma unroll
  for (int n = 0; n < 4; ++n) {
#pragma unroll
    for (int kk = 0; kk < 2; ++kk) {
      const int o = n * 16 + rA;
      const int colByte = (kk * 64 + g * 16) ^ ((o & 7) << 4);
      bfr[n][kk] = *reinterpret_cast<const bf16x8_t*>(Bbase + o * 128 + colByte);
    }
  }

  f32x4_t acc[4][4];
#pragma unroll
  for (int m = 0; m < 4; ++m)
#pragma unroll
    for (int n = 0; n < 4; ++n)
#pragma unroll
      for (int e = 0; e < 4; ++e) acc[m][n][e] = 0.0f;

#pragma unroll
  for (int kk = 0; kk < 2; ++kk)
#pragma unroll
    for (int m = 0; m < 4; ++m)
#pragma unroll
      for (int n = 0; n < 4; ++n)
        acc[m][n] = __builtin_amdgcn_mfma_f32_16x16x32_bf16(
            af[m][kk], bfr[n][kk], acc[m][n], 0, 0, 0);

  // ---- scatter-add: D row = 4*g + reg (within 16-row frag), col = rA ----
#pragma unroll
  for (int m = 0; m < 4; ++m) {
#pragma unroll
    for (int j = 0; j < 4; ++j) {
      const int rr = wid * 64 + m * 16 + g * 4 + j;
      const int rule = rule0 + rr;
      if (rule < RULES) {
        const int orow = out_idx[(size_t)k * RULES + rule];
        float* op = out + (size_t)orow * COUT + rA;
#pragma unroll
        for (int n = 0; n < 4; ++n) {
          atomicAdd(op + n * 16, acc[m][n][j]);
        }
      }
    }
  }
}

extern "C" void kernel_launch(void* const* d_in, const int* in_sizes, int n_in,
                              void* d_out, int out_size, void* d_ws, size_t ws_size,
                              hipStream_t stream) {
  const float* x = (const float*)d_in[0];
  const float* w = (const float*)d_in[1];
  const float* bias = (const float*)d_in[2];
  const int* in_idx = (const int*)d_in[3];
  const int* out_idx = (const int*)d_in[4];
  float* out = (float*)d_out;

  // init out with bias (harness poisons d_out before every launch)
  const int total4 = NOUT * COUT / 4;
  init_out_kernel<<<2048, 256, 0, stream>>>(bias, out, total4);

  // main fused gather-GEMM-scatter
  spconv_kernel<<<KOFF * BPK, 256, 0, stream>>>(x, w, in_idx, out_idx, out);
}